// Round 1
// baseline (2428.868 us; speedup 1.0000x reference)
//
#include <hip/hip_runtime.h>
#include <math.h>

// TriOut: z[L,L,Z] -> LN -> gated proj to C -> einsum('ilc,jlc->ijc') -> LN(C)
//         -> proj back to Z -> * sigmoid(zn@g_w+g_b)
// L=768, Z=128, C=32.  Output fp32 [L,L,Z].
//
// ws layout:
//   a_t  : bf16 [C][L*L]   ( 37,748,736 B)  a in c-major layout -> 32 batched A*A^T GEMMs
//   gate : bf16 [L*L][Z]   (150,994,944 B)  sigmoid(zn@g_w + g_b)
//   obuf : fp32 [C][L*L]   ( 75,497,472 B)  einsum result, c-major
// total 264,241,152 B

#define LDIM 768
#define LL   (768 * 768)
#define ZD   128
#define CD   32

typedef __bf16 bf16x8 __attribute__((ext_vector_type(8)));
typedef float  f32x4  __attribute__((ext_vector_type(4)));

__device__ __forceinline__ ushort f2bf(float f) {
    __bf16 h = (__bf16)f;                      // RNE convert
    return __builtin_bit_cast(ushort, h);
}
__device__ __forceinline__ float bf2f(ushort u) {
    return __builtin_bit_cast(float, ((unsigned)u) << 16);
}
__device__ __forceinline__ float sigm(float x) { return 1.0f / (1.0f + expf(-x)); }

// ---------------------------------------------------------------------------
// k1: per 32 rows of the flattened [L*L, Z] view:
//   LN(z) -> zn (LDS) -> dots vs 192 weight rows (a_w 0..31 | ag_w 32..63 | g_w 64..191)
//   -> a_t bf16 (c-major), gate bf16.
// Thread tiling phase B: thread = (rg 0..3, cg 0..63): 8 rows x 3 channels,
// zn read as float4 wave-uniform broadcast (conflict-free), 96 FMA / 8 LDS reads.
// ---------------------------------------------------------------------------
__global__ __launch_bounds__(256) void k1_ln_proj(
    const float* __restrict__ z,  const float* __restrict__ nw, const float* __restrict__ nb,
    const float* __restrict__ aw, const float* __restrict__ ab,
    const float* __restrict__ agw, const float* __restrict__ agb,
    const float* __restrict__ gw, const float* __restrict__ gb,
    ushort* __restrict__ a_t, ushort* __restrict__ gate)
{
    __shared__ float zn[32][132];   // pad 128->132: conflict-free float4 writes
    __shared__ float pr[32][193];   // pad 192->193: conflict-free col reads in phase C

    const int tid = threadIdx.x;
    const long rowbase = (long)blockIdx.x * 32;

    // ---- Phase A: LayerNorm, 8 threads per row, 16 elems each ----
    {
        const int r = tid >> 3, seg = tid & 7;
        const float4* zp4 = (const float4*)(z + (size_t)(rowbase + r) * ZD + seg * 16);
        float v[16];
        #pragma unroll
        for (int q = 0; q < 4; ++q) {
            float4 t4 = zp4[q];
            v[q * 4 + 0] = t4.x; v[q * 4 + 1] = t4.y;
            v[q * 4 + 2] = t4.z; v[q * 4 + 3] = t4.w;
        }
        float s = 0.f, ss = 0.f;
        #pragma unroll
        for (int e = 0; e < 16; ++e) { s += v[e]; ss += v[e] * v[e]; }
        #pragma unroll
        for (int off = 1; off < 8; off <<= 1) {
            s  += __shfl_xor(s, off);
            ss += __shfl_xor(ss, off);
        }
        const float mu  = s * (1.f / 128.f);
        const float var = ss * (1.f / 128.f) - mu * mu;
        const float rs  = rsqrtf(var + 1e-5f);
        #pragma unroll
        for (int q = 0; q < 4; ++q) {
            const int k = seg * 16 + q * 4;
            float4 o4;
            o4.x = (v[q * 4 + 0] - mu) * rs * nw[k + 0] + nb[k + 0];
            o4.y = (v[q * 4 + 1] - mu) * rs * nw[k + 1] + nb[k + 1];
            o4.z = (v[q * 4 + 2] - mu) * rs * nw[k + 2] + nb[k + 2];
            o4.w = (v[q * 4 + 3] - mu) * rs * nw[k + 3] + nb[k + 3];
            *(float4*)&zn[r][k] = o4;
        }
    }
    __syncthreads();

    // ---- Phase B: 192 dot products x 32 rows ----
    {
        const int rg = tid >> 6;           // 0..3 -> rows rg*8..+7
        const int cg = tid & 63;           // channels cg*3..+2
        const int ch0 = cg * 3;
        const float* wp[3];
        #pragma unroll
        for (int t = 0; t < 3; ++t) {
            const int ch = ch0 + t;
            wp[t] = (ch < 32) ? (aw + ch * ZD)
                  : (ch < 64) ? (agw + (ch - 32) * ZD)
                              : (gw + (ch - 64) * ZD);
        }
        float acc[3][8] = {};
        for (int k4 = 0; k4 < 32; ++k4) {
            float4 zr[8];
            #pragma unroll
            for (int r = 0; r < 8; ++r)
                zr[r] = *(const float4*)&zn[rg * 8 + r][k4 * 4];   // wave-uniform broadcast
            #pragma unroll
            for (int t = 0; t < 3; ++t) {
                const float4 w4 = *(const float4*)(wp[t] + k4 * 4);
                #pragma unroll
                for (int r = 0; r < 8; ++r)
                    acc[t][r] += w4.x * zr[r].x + w4.y * zr[r].y
                               + w4.z * zr[r].z + w4.w * zr[r].w;
            }
        }
        #pragma unroll
        for (int t = 0; t < 3; ++t)
            #pragma unroll
            for (int r = 0; r < 8; ++r)
                pr[rg * 8 + r][ch0 + t] = acc[t][r];
    }
    __syncthreads();

    // ---- Phase C1: gate = sigmoid(g_lin + g_b) -> bf16, [row][128] ----
    {
        const int r = tid >> 3, k0 = (tid & 7) * 16;
        union { ushort u[16]; uint4 q2[2]; } pk;
        #pragma unroll
        for (int e = 0; e < 16; ++e) {
            const int k = k0 + e;
            pk.u[e] = f2bf(sigm(pr[r][64 + k] + gb[k]));
        }
        ushort* dst = gate + (size_t)(rowbase + r) * ZD + k0;
        *(uint4*)dst       = pk.q2[0];
        *((uint4*)dst + 1) = pk.q2[1];
    }

    // ---- Phase C2: a = (pa + a_b) * sigmoid(pag + ag_b) -> bf16, c-major ----
    #pragma unroll
    for (int pass = 0; pass < 4; ++pass) {
        const int c = pass * 8 + (tid >> 5);   // 0..31
        const int r = tid & 31;
        const float pa  = pr[r][c]      + ab[c];
        const float pag = pr[r][32 + c] + agb[c];
        a_t[(size_t)c * LL + rowbase + r] = f2bf(pa * sigm(pag));
    }
}

// ---------------------------------------------------------------------------
// k2: 32 batched GEMMs  O_c = M_c * M_c^T,  M_c = a_t[c] as [768][768] bf16.
// 64x64 tile, BK=32, 4 waves (each 32x32 quadrant = 2x2 mfma_f32_16x16x32_bf16).
// Double-buffered LDS, reg-staged (simple; global_load_lds is the next step).
// Frag layout 16x16x32 bf16: A lane: row=lane&15, k=(lane>>4)*8+[0..7];
//                            B lane: col=lane&15, same k  -> both read 8
//                            contiguous bf16 from a row of M_c.
// D layout (verified): col=lane&15, row=(lane>>4)*4+reg.
// ---------------------------------------------------------------------------
__global__ __launch_bounds__(256) void k2_einsum(
    const ushort* __restrict__ a_t, float* __restrict__ obuf)
{
    __shared__ ushort As[2][64][32];
    __shared__ ushort Bs[2][64][32];

    const int tid = threadIdx.x;
    const int c  = blockIdx.z;
    const int i0 = blockIdx.y * 64, j0 = blockIdx.x * 64;
    const ushort* base = a_t + (size_t)c * LL;

    const int srow = tid >> 2, scol = (tid & 3) * 8;
    const ushort* gA = base + (size_t)(i0 + srow) * LDIM + scol;
    const ushort* gB = base + (size_t)(j0 + srow) * LDIM + scol;

    const int wave = tid >> 6, lane = tid & 63;
    const int wi = (wave >> 1) * 32, wj = (wave & 1) * 32;
    const int fr = lane & 15, k8 = (lane >> 4) * 8;

    f32x4 acc[2][2];
    #pragma unroll
    for (int m = 0; m < 2; ++m)
        #pragma unroll
        for (int n = 0; n < 2; ++n)
            acc[m][n] = (f32x4){0.f, 0.f, 0.f, 0.f};

    // stage k-chunk kc into buffer b
    auto stage = [&](int b, int kc) {
        *(uint4*)&As[b][srow][scol] = *(const uint4*)(gA + kc * 32);
        *(uint4*)&Bs[b][srow][scol] = *(const uint4*)(gB + kc * 32);
    };

    stage(0, 0);
    __syncthreads();
    for (int kc = 0; kc < 24; ++kc) {
        const int cur = kc & 1;
        if (kc + 1 < 24) stage(cur ^ 1, kc + 1);

        bf16x8 av[2], bv[2];
        #pragma unroll
        for (int m = 0; m < 2; ++m)
            av[m] = *(const bf16x8*)&As[cur][wi + m * 16 + fr][k8];
        #pragma unroll
        for (int n = 0; n < 2; ++n)
            bv[n] = *(const bf16x8*)&Bs[cur][wj + n * 16 + fr][k8];

        #pragma unroll
        for (int m = 0; m < 2; ++m)
            #pragma unroll
            for (int n = 0; n < 2; ++n)
                acc[m][n] = __builtin_amdgcn_mfma_f32_16x16x32_bf16(
                    av[m], bv[n], acc[m][n], 0, 0, 0);
        __syncthreads();
    }

    float* ob = obuf + (size_t)c * LL;
    #pragma unroll
    for (int m = 0; m < 2; ++m)
        #pragma unroll
        for (int n = 0; n < 2; ++n)
            #pragma unroll
            for (int q = 0; q < 4; ++q) {
                const int row = i0 + wi + m * 16 + (lane >> 4) * 4 + q;
                const int col = j0 + wj + n * 16 + fr;
                ob[(size_t)row * LDIM + col] = acc[m][n][q];
            }
}

// ---------------------------------------------------------------------------
// k3: per (i, j): LN over C=32 (in-thread), project to Z=128 with o_w,
//     multiply by gate.  Block = one i, 64 j's; thread = (jj, 32-k chunk).
// ---------------------------------------------------------------------------
__global__ __launch_bounds__(256) void k3_out(
    const float* __restrict__ obuf,
    const float* __restrict__ onw, const float* __restrict__ onb,
    const float* __restrict__ ow,  const float* __restrict__ obias,
    const ushort* __restrict__ gate, float* __restrict__ out)
{
    __shared__ float Ol[64][33];
    const int tid = threadIdx.x;
    const int i  = blockIdx.y;
    const int j0 = blockIdx.x * 64;

    {   // coalesced gather of o[c][i][j0..j0+63] into LDS
        const int jj = tid & 63, cgi = tid >> 6;
        const size_t off = (size_t)i * LDIM + j0 + jj;
        #pragma unroll
        for (int cc = 0; cc < 8; ++cc) {
            const int ch = cgi * 8 + cc;
            Ol[jj][ch] = obuf[(size_t)ch * LL + off];
        }
    }
    __syncthreads();

    const int jj = tid >> 2;
    const int kg = (tid & 3) * 32;

    float ov[32];
    float s = 0.f, ss = 0.f;
    #pragma unroll
    for (int cc = 0; cc < 32; ++cc) {
        ov[cc] = Ol[jj][cc];
        s += ov[cc]; ss += ov[cc] * ov[cc];
    }
    const float mu  = s * (1.f / 32.f);
    const float var = ss * (1.f / 32.f) - mu * mu;
    const float rs  = rsqrtf(var + 1e-5f);
    #pragma unroll
    for (int cc = 0; cc < 32; ++cc)
        ov[cc] = (ov[cc] - mu) * rs * onw[cc] + onb[cc];

    const size_t rowoff = ((size_t)i * LDIM + j0 + jj) * ZD;

    union { uint4 v[4]; ushort u[32]; } G;
    #pragma unroll
    for (int q = 0; q < 4; ++q)
        G.v[q] = *(const uint4*)&gate[rowoff + kg + q * 8];

    float res[32];
    #pragma unroll
    for (int kk = 0; kk < 32; ++kk) {
        const int k = kg + kk;
        const float* wr = ow + k * CD;
        float a2 = obias[k];
        #pragma unroll
        for (int cc = 0; cc < 32; ++cc) a2 += ov[cc] * wr[cc];
        res[kk] = a2 * bf2f(G.u[kk]);
    }
    #pragma unroll
    for (int q = 0; q < 8; ++q) {
        float4 w;
        w.x = res[q * 4 + 0]; w.y = res[q * 4 + 1];
        w.z = res[q * 4 + 2]; w.w = res[q * 4 + 3];
        *(float4*)&out[rowoff + kg + q * 4] = w;
    }
}

extern "C" void kernel_launch(void* const* d_in, const int* in_sizes, int n_in,
                              void* d_out, int out_size, void* d_ws, size_t ws_size,
                              hipStream_t stream) {
    (void)in_sizes; (void)n_in; (void)out_size; (void)ws_size;
    const float* z   = (const float*)d_in[0];
    const float* nw  = (const float*)d_in[1];
    const float* nb  = (const float*)d_in[2];
    const float* onw = (const float*)d_in[3];
    const float* onb = (const float*)d_in[4];
    const float* aw  = (const float*)d_in[5];
    const float* ab  = (const float*)d_in[6];
    const float* agw = (const float*)d_in[7];
    const float* agb = (const float*)d_in[8];
    const float* gw  = (const float*)d_in[9];
    const float* gb  = (const float*)d_in[10];
    const float* ow  = (const float*)d_in[11];
    const float* ob  = (const float*)d_in[12];

    char* ws = (char*)d_ws;
    ushort* a_t  = (ushort*)ws;                                   // 37,748,736 B
    ushort* gate = (ushort*)(ws + 37748736);                      // 150,994,944 B
    float*  obuf = (float*)(ws + 37748736 + 150994944);           // 75,497,472 B

    k1_ln_proj<<<LL / 32, 256, 0, stream>>>(z, nw, nb, aw, ab, agw, agb, gw, gb,
                                            a_t, gate);
    k2_einsum<<<dim3(12, 12, 32), 256, 0, stream>>>(a_t, obuf);
    k3_out<<<dim3(12, LDIM), 256, 0, stream>>>(obuf, onw, onb, ow, ob, gate,
                                               (float*)d_out);
}

// Round 2
// 1373.357 us; speedup vs baseline: 1.7686x; 1.7686x over previous
//
#include <hip/hip_runtime.h>
#include <math.h>

// TriOut: z[L,L,Z] -> LN -> gated proj to C -> einsum('ilc,jlc->ijc') -> LN(C)
//         -> proj back to Z -> * sigmoid(zn@g_w+g_b)
// L=768, Z=128, C=32.  Output fp32 [L,L,Z].
//
// ws layout:
//   a_t  : bf16 [C][L*L]   ( 37,748,736 B)  a, c-major -> 32 batched A*A^T GEMMs
//   gate : bf16 [L*L][Z]   (150,994,944 B)  sigmoid(zn@g_w + g_b)
//   obuf : fp32 [C][L*L]   ( 75,497,472 B)  einsum result, c-major
//   wcat : bf16 [192][128] aliased onto obuf start (only live k0->k1, k2 clobbers)

#define LDIM 768
#define LL   (768 * 768)
#define ZD   128
#define CD   32

typedef __bf16 bf16x8 __attribute__((ext_vector_type(8)));
typedef float  f32x4  __attribute__((ext_vector_type(4)));

__device__ __forceinline__ ushort f2bf(float f) {
    __bf16 h = (__bf16)f;                      // RNE convert
    return __builtin_bit_cast(ushort, h);
}
__device__ __forceinline__ float bf2f(ushort u) {
    return __builtin_bit_cast(float, ((unsigned)u) << 16);
}
__device__ __forceinline__ float sigm(float x) { return 1.0f / (1.0f + expf(-x)); }

// ---------------------------------------------------------------------------
// k0: pack [a_w ; ag_w ; g_w] -> bf16 wcat[192][128]   (runs once, 96 blocks)
// ---------------------------------------------------------------------------
__global__ __launch_bounds__(256) void k0_wconv(
    const float* __restrict__ aw, const float* __restrict__ agw,
    const float* __restrict__ gw, ushort* __restrict__ wcat)
{
    const int idx = blockIdx.x * 256 + threadIdx.x;
    if (idx >= 192 * ZD) return;
    const int ch = idx >> 7, k = idx & 127;
    const float v = (ch < 32) ? aw[ch * ZD + k]
                  : (ch < 64) ? agw[(ch - 32) * ZD + k]
                              : gw[(ch - 64) * ZD + k];
    wcat[idx] = f2bf(v);
}

// ---------------------------------------------------------------------------
// k1: per 64 rows of the flattened [L*L, Z] view:
//   LN(z) fp32 -> zn bf16 (LDS, padded) ; weights bf16 staged to LDS;
//   4 waves x (16 rows x 192 ch) via mfma_f32_16x16x32_bf16 (12 n-tiles x 4 k);
//   epilogue: a=(pa+ab)*sigm(pag+agb) -> a_t (c-major), sigm(g+gb) -> gate.
// A-frag: row=lane&15, k=(lane>>4)*8+j ; B-frag: col=lane&15, same k.
// D: col=lane&15, row=(lane>>4)*4+q  (verified mapping).
// LDS: zn 64x136x2 = 17408 B, wl 192x136x2 = 52224 B -> 69632 B, 2 blocks/CU.
// ---------------------------------------------------------------------------
__global__ __launch_bounds__(256) void k1_ln_proj(
    const float* __restrict__ z, const float* __restrict__ nw, const float* __restrict__ nb,
    const ushort* __restrict__ wcat,
    const float* __restrict__ ab, const float* __restrict__ agb, const float* __restrict__ gb,
    ushort* __restrict__ a_t, ushort* __restrict__ gate)
{
    __shared__ ushort zn[64][136];   // pad 128->136: 16B-aligned rows, ~free conflicts
    __shared__ ushort wl[192][136];

    const int tid = threadIdx.x;
    const size_t rowbase = (size_t)blockIdx.x * 64;

    // ---- stage weights 192x128 bf16 -> wl ----
    #pragma unroll
    for (int it = 0; it < 12; ++it) {
        const int idx = it * 256 + tid;          // uint4 index (3072 total)
        const int r = idx >> 4, cq = idx & 15;
        *(uint4*)&wl[r][cq * 8] = *(const uint4*)(wcat + r * ZD + cq * 8);
    }

    // ---- LayerNorm: 4 threads/row, 32 elems each, fp32 ----
    {
        const int r = tid >> 2, seg = tid & 3;
        const float4* zp = (const float4*)(z + (rowbase + r) * ZD + seg * 32);
        float v[32];
        #pragma unroll
        for (int q = 0; q < 8; ++q) {
            const float4 t = zp[q];
            v[q * 4 + 0] = t.x; v[q * 4 + 1] = t.y;
            v[q * 4 + 2] = t.z; v[q * 4 + 3] = t.w;
        }
        float s = 0.f, ss = 0.f;
        #pragma unroll
        for (int e = 0; e < 32; ++e) { s += v[e]; ss += v[e] * v[e]; }
        s += __shfl_xor(s, 1); ss += __shfl_xor(ss, 1);
        s += __shfl_xor(s, 2); ss += __shfl_xor(ss, 2);
        const float mu  = s * (1.f / 128.f);
        const float var = ss * (1.f / 128.f) - mu * mu;
        const float rs  = rsqrtf(var + 1e-5f);
        union { ushort u[32]; uint4 q4[4]; } pk;
        #pragma unroll
        for (int e = 0; e < 32; ++e) {
            const int k = seg * 32 + e;
            pk.u[e] = f2bf((v[e] - mu) * rs * nw[k] + nb[k]);
        }
        #pragma unroll
        for (int q = 0; q < 4; ++q)
            *(uint4*)&zn[r][seg * 32 + q * 8] = pk.q4[q];
    }
    __syncthreads();

    // ---- MFMA: wave w -> rows w*16..+15, all 192 channels ----
    const int lane = tid & 63, wave = tid >> 6;
    const int fr = lane & 15, hi = lane >> 4;
    const int wrow = wave * 16;

    bf16x8 af[4];
    #pragma unroll
    for (int kk = 0; kk < 4; ++kk)
        af[kk] = *(const bf16x8*)&zn[wrow + fr][kk * 32 + hi * 8];

    f32x4 acc[12];
    #pragma unroll
    for (int n = 0; n < 12; ++n) acc[n] = (f32x4){0.f, 0.f, 0.f, 0.f};

    #pragma unroll
    for (int n = 0; n < 12; ++n)
        #pragma unroll
        for (int kk = 0; kk < 4; ++kk) {
            const bf16x8 bv = *(const bf16x8*)&wl[n * 16 + fr][kk * 32 + hi * 8];
            acc[n] = __builtin_amdgcn_mfma_f32_16x16x32_bf16(af[kk], bv, acc[n], 0, 0, 0);
        }

    // ---- epilogue: a * sigmoid(ag) -> a_t (c-major, 4 rows packed) ----
    const int orow = wrow + hi * 4;
    #pragma unroll
    for (int n = 0; n < 2; ++n) {
        const int ch = n * 16 + fr;
        const float abv = ab[ch], agbv = agb[ch];
        union { ushort u[4]; uint2 d; } pk;
        #pragma unroll
        for (int q = 0; q < 4; ++q)
            pk.u[q] = f2bf((acc[n][q] + abv) * sigm(acc[n + 2][q] + agbv));
        *(uint2*)&a_t[(size_t)ch * LL + rowbase + orow] = pk.d;
    }

    // ---- epilogue: sigmoid(g) -> LDS transpose -> coalesced gate writes ----
    ushort gv[8][4];
    #pragma unroll
    for (int n2 = 0; n2 < 8; ++n2) {
        const int gch = n2 * 16 + fr;
        const float gbv = gb[gch];
        #pragma unroll
        for (int q = 0; q < 4; ++q)
            gv[n2][q] = f2bf(sigm(acc[4 + n2][q] + gbv));
    }
    __syncthreads();                       // all waves done reading zn
    ushort* gl = &zn[0][0];                // reuse zn LDS as [64][136]
    #pragma unroll
    for (int n2 = 0; n2 < 8; ++n2)
        #pragma unroll
        for (int q = 0; q < 4; ++q)
            gl[(size_t)(orow + q) * 136 + n2 * 16 + fr] = gv[n2][q];
    __syncthreads();
    #pragma unroll
    for (int it = 0; it < 4; ++it) {
        const int idx = it * 256 + tid;    // uint4 index (1024 total)
        const int r = idx >> 4, cq = idx & 15;
        *(uint4*)&gate[(rowbase + r) * ZD + cq * 8] = *(const uint4*)&gl[(size_t)r * 136 + cq * 8];
    }
}

// ---------------------------------------------------------------------------
// k2: 32 batched GEMMs  O_c = M_c * M_c^T,  M_c = a_t[c] as [768][768] bf16.
// 64x64 tile, BK=32, 4 waves (each 32x32 quadrant = 2x2 mfma_f32_16x16x32_bf16).
// ---------------------------------------------------------------------------
__global__ __launch_bounds__(256) void k2_einsum(
    const ushort* __restrict__ a_t, float* __restrict__ obuf)
{
    __shared__ ushort As[2][64][32];
    __shared__ ushort Bs[2][64][32];

    const int tid = threadIdx.x;
    const int c  = blockIdx.z;
    const int i0 = blockIdx.y * 64, j0 = blockIdx.x * 64;
    const ushort* base = a_t + (size_t)c * LL;

    const int srow = tid >> 2, scol = (tid & 3) * 8;
    const ushort* gA = base + (size_t)(i0 + srow) * LDIM + scol;
    const ushort* gB = base + (size_t)(j0 + srow) * LDIM + scol;

    const int wave = tid >> 6, lane = tid & 63;
    const int wi = (wave >> 1) * 32, wj = (wave & 1) * 32;
    const int fr = lane & 15, k8 = (lane >> 4) * 8;

    f32x4 acc[2][2];
    #pragma unroll
    for (int m = 0; m < 2; ++m)
        #pragma unroll
        for (int n = 0; n < 2; ++n)
            acc[m][n] = (f32x4){0.f, 0.f, 0.f, 0.f};

    auto stage = [&](int b, int kc) {
        *(uint4*)&As[b][srow][scol] = *(const uint4*)(gA + kc * 32);
        *(uint4*)&Bs[b][srow][scol] = *(const uint4*)(gB + kc * 32);
    };

    stage(0, 0);
    __syncthreads();
    for (int kc = 0; kc < 24; ++kc) {
        const int cur = kc & 1;
        if (kc + 1 < 24) stage(cur ^ 1, kc + 1);

        bf16x8 av[2], bv[2];
        #pragma unroll
        for (int m = 0; m < 2; ++m)
            av[m] = *(const bf16x8*)&As[cur][wi + m * 16 + fr][k8];
        #pragma unroll
        for (int n = 0; n < 2; ++n)
            bv[n] = *(const bf16x8*)&Bs[cur][wj + n * 16 + fr][k8];

        #pragma unroll
        for (int m = 0; m < 2; ++m)
            #pragma unroll
            for (int n = 0; n < 2; ++n)
                acc[m][n] = __builtin_amdgcn_mfma_f32_16x16x32_bf16(
                    av[m], bv[n], acc[m][n], 0, 0, 0);
        __syncthreads();
    }

    float* ob = obuf + (size_t)c * LL;
    #pragma unroll
    for (int m = 0; m < 2; ++m)
        #pragma unroll
        for (int n = 0; n < 2; ++n)
            #pragma unroll
            for (int q = 0; q < 4; ++q) {
                const int row = i0 + wi + m * 16 + (lane >> 4) * 4 + q;
                const int col = j0 + wj + n * 16 + fr;
                ob[(size_t)row * LDIM + col] = acc[m][n][q];
            }
}

// ---------------------------------------------------------------------------
// k3: per (i, j): LN over C=32 (in-thread), project to Z=128 with o_w,
//     multiply by gate.  Block = one i, 64 j's; thread = (jj, 32-k chunk).
// ---------------------------------------------------------------------------
__global__ __launch_bounds__(256) void k3_out(
    const float* __restrict__ obuf,
    const float* __restrict__ onw, const float* __restrict__ onb,
    const float* __restrict__ ow,  const float* __restrict__ obias,
    const ushort* __restrict__ gate, float* __restrict__ out)
{
    __shared__ float Ol[64][33];
    const int tid = threadIdx.x;
    const int i  = blockIdx.y;
    const int j0 = blockIdx.x * 64;

    {   // coalesced gather of o[c][i][j0..j0+63] into LDS
        const int jj = tid & 63, cgi = tid >> 6;
        const size_t off = (size_t)i * LDIM + j0 + jj;
        #pragma unroll
        for (int cc = 0; cc < 8; ++cc) {
            const int ch = cgi * 8 + cc;
            Ol[jj][ch] = obuf[(size_t)ch * LL + off];
        }
    }
    __syncthreads();

    const int jj = tid >> 2;
    const int kg = (tid & 3) * 32;

    float ov[32];
    float s = 0.f, ss = 0.f;
    #pragma unroll
    for (int cc = 0; cc < 32; ++cc) {
        ov[cc] = Ol[jj][cc];
        s += ov[cc]; ss += ov[cc] * ov[cc];
    }
    const float mu  = s * (1.f / 32.f);
    const float var = ss * (1.f / 32.f) - mu * mu;
    const float rs  = rsqrtf(var + 1e-5f);
    #pragma unroll
    for (int cc = 0; cc < 32; ++cc)
        ov[cc] = (ov[cc] - mu) * rs * onw[cc] + onb[cc];

    const size_t rowoff = ((size_t)i * LDIM + j0 + jj) * ZD;

    union { uint4 v[4]; ushort u[32]; } G;
    #pragma unroll
    for (int q = 0; q < 4; ++q)
        G.v[q] = *(const uint4*)&gate[rowoff + kg + q * 8];

    float res[32];
    #pragma unroll
    for (int kk = 0; kk < 32; ++kk) {
        const int k = kg + kk;
        const float* wr = ow + k * CD;
        float a2 = obias[k];
        #pragma unroll
        for (int cc = 0; cc < 32; ++cc) a2 += ov[cc] * wr[cc];
        res[kk] = a2 * bf2f(G.u[kk]);
    }
    #pragma unroll
    for (int q = 0; q < 8; ++q) {
        float4 w;
        w.x = res[q * 4 + 0]; w.y = res[q * 4 + 1];
        w.z = res[q * 4 + 2]; w.w = res[q * 4 + 3];
        *(float4*)&out[rowoff + kg + q * 4] = w;
    }
}

extern "C" void kernel_launch(void* const* d_in, const int* in_sizes, int n_in,
                              void* d_out, int out_size, void* d_ws, size_t ws_size,
                              hipStream_t stream) {
    (void)in_sizes; (void)n_in; (void)out_size; (void)ws_size;
    const float* z   = (const float*)d_in[0];
    const float* nw  = (const float*)d_in[1];
    const float* nb  = (const float*)d_in[2];
    const float* onw = (const float*)d_in[3];
    const float* onb = (const float*)d_in[4];
    const float* aw  = (const float*)d_in[5];
    const float* ab  = (const float*)d_in[6];
    const float* agw = (const float*)d_in[7];
    const float* agb = (const float*)d_in[8];
    const float* gw  = (const float*)d_in[9];
    const float* gb  = (const float*)d_in[10];
    const float* ow  = (const float*)d_in[11];
    const float* ob  = (const float*)d_in[12];

    char* ws = (char*)d_ws;
    ushort* a_t  = (ushort*)ws;                                   // 37,748,736 B
    ushort* gate = (ushort*)(ws + 37748736);                      // 150,994,944 B
    float*  obuf = (float*)(ws + 37748736 + 150994944);           // 75,497,472 B
    ushort* wcat = (ushort*)obuf;  // aliased: live only k0->k1, k2 clobbers

    k0_wconv<<<96, 256, 0, stream>>>(aw, agw, gw, wcat);
    k1_ln_proj<<<LL / 64, 256, 0, stream>>>(z, nw, nb, wcat, ab, agb, gb,
                                            a_t, gate);
    k2_einsum<<<dim3(12, 12, 32), 256, 0, stream>>>(a_t, obuf);
    k3_out<<<dim3(12, LDIM), 256, 0, stream>>>(obuf, onw, onb, ow, ob, gate,
                                               (float*)d_out);
}

// Round 3
// 382.188 us; speedup vs baseline: 6.3552x; 3.5934x over previous
//
#include <hip/hip_runtime.h>
#include <math.h>

// TriOut: z[L,L,Z] -> LN -> gated proj to C -> einsum('ilc,jlc->ijc') -> LN(C)
//         -> proj back to Z -> * sigmoid(zn@g_w+g_b)
// L=768, Z=128, C=32.  Output fp32 [L,L,Z].
//
// ws layout:
//   a_t  : bf16 [C][L*L]   ( 37,748,736 B)  a, c-major -> 32 batched A*A^T GEMMs
//   gate : bf16 [L*L][Z]   (150,994,944 B)  sigmoid(zn@g_w + g_b)
//   obuf : fp32 [C][L*L]   ( 75,497,472 B)  einsum result, c-major
//   wcat : bf16 [192][128] aliased onto obuf start (only live k0->k1, k2 clobbers)

#define LDIM 768
#define LL   (768 * 768)
#define ZD   128
#define CD   32

typedef __bf16 bf16x8 __attribute__((ext_vector_type(8)));
typedef float  f32x4  __attribute__((ext_vector_type(4)));

__device__ __forceinline__ ushort f2bf(float f) {
    __bf16 h = (__bf16)f;                      // RNE convert
    return __builtin_bit_cast(ushort, h);
}
__device__ __forceinline__ float bf2f(ushort u) {
    return __builtin_bit_cast(float, ((unsigned)u) << 16);
}
__device__ __forceinline__ float sigm(float x) { return 1.0f / (1.0f + expf(-x)); }

// ---------------------------------------------------------------------------
// k0: pack [a_w ; ag_w ; g_w] -> bf16 wcat[192][128]   (runs once, 96 blocks)
// ---------------------------------------------------------------------------
__global__ __launch_bounds__(256) void k0_wconv(
    const float* __restrict__ aw, const float* __restrict__ agw,
    const float* __restrict__ gw, ushort* __restrict__ wcat)
{
    const int idx = blockIdx.x * 256 + threadIdx.x;
    if (idx >= 192 * ZD) return;
    const int ch = idx >> 7, k = idx & 127;
    const float v = (ch < 32) ? aw[ch * ZD + k]
                  : (ch < 64) ? agw[(ch - 32) * ZD + k]
                              : gw[(ch - 64) * ZD + k];
    wcat[idx] = f2bf(v);
}

// ---------------------------------------------------------------------------
// k1: per 64 rows of the flattened [L*L, Z] view:
//   LN(z) fp32 -> zn bf16 (LDS) ; weights bf16 staged to LDS;
//   4 waves x (16 rows x 192 ch) via mfma_f32_16x16x32_bf16 (12 n-tiles x 4 k);
//   epilogue: a=(pa+ab)*sigm(pag+agb) -> a_t (c-major), sigm(g+gb) -> gate.
// ---------------------------------------------------------------------------
__global__ __launch_bounds__(256) void k1_ln_proj(
    const float* __restrict__ z, const float* __restrict__ nw, const float* __restrict__ nb,
    const ushort* __restrict__ wcat,
    const float* __restrict__ ab, const float* __restrict__ agb, const float* __restrict__ gb,
    ushort* __restrict__ a_t, ushort* __restrict__ gate)
{
    __shared__ ushort zn[64][136];   // pad 128->136: 16B-aligned rows
    __shared__ ushort wl[192][136];

    const int tid = threadIdx.x;
    const size_t rowbase = (size_t)blockIdx.x * 64;

    // ---- stage weights 192x128 bf16 -> wl ----
    #pragma unroll
    for (int it = 0; it < 12; ++it) {
        const int idx = it * 256 + tid;          // uint4 index (3072 total)
        const int r = idx >> 4, cq = idx & 15;
        *(uint4*)&wl[r][cq * 8] = *(const uint4*)(wcat + r * ZD + cq * 8);
    }

    // ---- LayerNorm: 4 threads/row, 32 elems each, fp32 ----
    {
        const int r = tid >> 2, seg = tid & 3;
        const float4* zp = (const float4*)(z + (rowbase + r) * ZD + seg * 32);
        float v[32];
        #pragma unroll
        for (int q = 0; q < 8; ++q) {
            const float4 t = zp[q];
            v[q * 4 + 0] = t.x; v[q * 4 + 1] = t.y;
            v[q * 4 + 2] = t.z; v[q * 4 + 3] = t.w;
        }
        float s = 0.f, ss = 0.f;
        #pragma unroll
        for (int e = 0; e < 32; ++e) { s += v[e]; ss += v[e] * v[e]; }
        s += __shfl_xor(s, 1); ss += __shfl_xor(ss, 1);
        s += __shfl_xor(s, 2); ss += __shfl_xor(ss, 2);
        const float mu  = s * (1.f / 128.f);
        const float var = ss * (1.f / 128.f) - mu * mu;
        const float rs  = rsqrtf(var + 1e-5f);
        union { ushort u[32]; uint4 q4[4]; } pk;
        #pragma unroll
        for (int e = 0; e < 32; ++e) {
            const int k = seg * 32 + e;
            pk.u[e] = f2bf((v[e] - mu) * rs * nw[k] + nb[k]);
        }
        #pragma unroll
        for (int q = 0; q < 4; ++q)
            *(uint4*)&zn[r][seg * 32 + q * 8] = pk.q4[q];
    }
    __syncthreads();

    // ---- MFMA: wave w -> rows w*16..+15, all 192 channels ----
    const int lane = tid & 63, wave = tid >> 6;
    const int fr = lane & 15, hi = lane >> 4;
    const int wrow = wave * 16;

    bf16x8 af[4];
    #pragma unroll
    for (int kk = 0; kk < 4; ++kk)
        af[kk] = *(const bf16x8*)&zn[wrow + fr][kk * 32 + hi * 8];

    f32x4 acc[12];
    #pragma unroll
    for (int n = 0; n < 12; ++n) acc[n] = (f32x4){0.f, 0.f, 0.f, 0.f};

    #pragma unroll
    for (int n = 0; n < 12; ++n)
        #pragma unroll
        for (int kk = 0; kk < 4; ++kk) {
            const bf16x8 bv = *(const bf16x8*)&wl[n * 16 + fr][kk * 32 + hi * 8];
            acc[n] = __builtin_amdgcn_mfma_f32_16x16x32_bf16(af[kk], bv, acc[n], 0, 0, 0);
        }

    // ---- epilogue: a * sigmoid(ag) -> a_t (c-major, 4 rows packed) ----
    const int orow = wrow + hi * 4;
    #pragma unroll
    for (int n = 0; n < 2; ++n) {
        const int ch = n * 16 + fr;
        const float abv = ab[ch], agbv = agb[ch];
        union { ushort u[4]; uint2 d; } pk;
        #pragma unroll
        for (int q = 0; q < 4; ++q)
            pk.u[q] = f2bf((acc[n][q] + abv) * sigm(acc[n + 2][q] + agbv));
        *(uint2*)&a_t[(size_t)ch * LL + rowbase + orow] = pk.d;
    }

    // ---- epilogue: sigmoid(g) -> LDS transpose -> coalesced gate writes ----
    ushort gv[8][4];
    #pragma unroll
    for (int n2 = 0; n2 < 8; ++n2) {
        const int gch = n2 * 16 + fr;
        const float gbv = gb[gch];
        #pragma unroll
        for (int q = 0; q < 4; ++q)
            gv[n2][q] = f2bf(sigm(acc[4 + n2][q] + gbv));
    }
    __syncthreads();                       // all waves done reading zn
    ushort* gl = &zn[0][0];                // reuse zn LDS as [64][136]
    #pragma unroll
    for (int n2 = 0; n2 < 8; ++n2)
        #pragma unroll
        for (int q = 0; q < 4; ++q)
            gl[(size_t)(orow + q) * 136 + n2 * 16 + fr] = gv[n2][q];
    __syncthreads();
    #pragma unroll
    for (int it = 0; it < 4; ++it) {
        const int idx = it * 256 + tid;    // uint4 index (1024 total)
        const int r = idx >> 4, cq = idx & 15;
        *(uint4*)&gate[(rowbase + r) * ZD + cq * 8] = *(const uint4*)&gl[(size_t)r * 136 + cq * 8];
    }
}

// ---------------------------------------------------------------------------
// k2: 32 batched GEMMs  O_c = M_c * M_c^T,  M_c = a_t[c] as [768][768] bf16.
// 64x64 tile, BK=32, 4 waves (each 32x32 quadrant = 2x2 mfma_f32_16x16x32_bf16).
// ---------------------------------------------------------------------------
__global__ __launch_bounds__(256) void k2_einsum(
    const ushort* __restrict__ a_t, float* __restrict__ obuf)
{
    __shared__ ushort As[2][64][32];
    __shared__ ushort Bs[2][64][32];

    const int tid = threadIdx.x;
    const int c  = blockIdx.z;
    const int i0 = blockIdx.y * 64, j0 = blockIdx.x * 64;
    const ushort* base = a_t + (size_t)c * LL;

    const int srow = tid >> 2, scol = (tid & 3) * 8;
    const ushort* gA = base + (size_t)(i0 + srow) * LDIM + scol;
    const ushort* gB = base + (size_t)(j0 + srow) * LDIM + scol;

    const int wave = tid >> 6, lane = tid & 63;
    const int wi = (wave >> 1) * 32, wj = (wave & 1) * 32;
    const int fr = lane & 15, k8 = (lane >> 4) * 8;

    f32x4 acc[2][2];
    #pragma unroll
    for (int m = 0; m < 2; ++m)
        #pragma unroll
        for (int n = 0; n < 2; ++n)
            acc[m][n] = (f32x4){0.f, 0.f, 0.f, 0.f};

    auto stage = [&](int b, int kc) {
        *(uint4*)&As[b][srow][scol] = *(const uint4*)(gA + kc * 32);
        *(uint4*)&Bs[b][srow][scol] = *(const uint4*)(gB + kc * 32);
    };

    stage(0, 0);
    __syncthreads();
    for (int kc = 0; kc < 24; ++kc) {
        const int cur = kc & 1;
        if (kc + 1 < 24) stage(cur ^ 1, kc + 1);

        bf16x8 av[2], bv[2];
        #pragma unroll
        for (int m = 0; m < 2; ++m)
            av[m] = *(const bf16x8*)&As[cur][wi + m * 16 + fr][k8];
        #pragma unroll
        for (int n = 0; n < 2; ++n)
            bv[n] = *(const bf16x8*)&Bs[cur][wj + n * 16 + fr][k8];

        #pragma unroll
        for (int m = 0; m < 2; ++m)
            #pragma unroll
            for (int n = 0; n < 2; ++n)
                acc[m][n] = __builtin_amdgcn_mfma_f32_16x16x32_bf16(
                    av[m], bv[n], acc[m][n], 0, 0, 0);
        __syncthreads();
    }

    float* ob = obuf + (size_t)c * LL;
    #pragma unroll
    for (int m = 0; m < 2; ++m)
        #pragma unroll
        for (int n = 0; n < 2; ++n)
            #pragma unroll
            for (int q = 0; q < 4; ++q) {
                const int row = i0 + wi + m * 16 + (lane >> 4) * 4 + q;
                const int col = j0 + wj + n * 16 + fr;
                ob[(size_t)row * LDIM + col] = acc[m][n][q];
            }
}

// ---------------------------------------------------------------------------
// k3: per 64 flat rows of [L*L, ...]:
//   gather obuf (c-major) -> LDS, LN over C=32 (affine) -> bf16 An[64][36],
//   o_w staged bf16 Bw[128][36]; wave w: rows w*16..+15 x 128 out = 8 MFMA
//   (single k-step, K=32); +o_b -> fp32 Res (aliased over gather buf);
//   final: Res * gate -> out, fully coalesced float4.
// ---------------------------------------------------------------------------
__global__ __launch_bounds__(256) void k3_out(
    const float* __restrict__ obuf,
    const float* __restrict__ onw, const float* __restrict__ onb,
    const float* __restrict__ ow,  const float* __restrict__ obias,
    const ushort* __restrict__ gate, float* __restrict__ out)
{
    __shared__ union { float Ol[64][40]; float Res[64][132]; } u;
    __shared__ ushort An[64][36];
    __shared__ ushort Bw[128][36];

    const int tid = threadIdx.x;
    const size_t rowbase = (size_t)blockIdx.x * 64;

    // ---- gather obuf: wave cg loads channels cg*8..+7 for all 64 rows ----
    {
        const int jj = tid & 63, cg = tid >> 6;
        const size_t off = rowbase + jj;
        #pragma unroll
        for (int cc = 0; cc < 8; ++cc) {
            const int ch = cg * 8 + cc;
            u.Ol[jj][ch] = obuf[(size_t)ch * LL + off];
        }
    }
    // ---- stage o_w -> bf16 Bw: thread t -> row t>>1, 16-ch half t&1 ----
    {
        const int r = tid >> 1, h = tid & 1;
        const float* src = ow + r * CD + h * 16;
        union { ushort us[16]; uint4 q[2]; } pk;
        #pragma unroll
        for (int e = 0; e < 16; ++e) pk.us[e] = f2bf(src[e]);
        *(uint4*)&Bw[r][h * 16]     = pk.q[0];
        *(uint4*)&Bw[r][h * 16 + 8] = pk.q[1];
    }
    __syncthreads();

    // ---- LN over C=32: 4 threads/row, 8 ch each, affine -> bf16 An ----
    {
        const int r = tid >> 2, seg = tid & 3;
        float v[8];
        #pragma unroll
        for (int e = 0; e < 8; ++e) v[e] = u.Ol[r][seg * 8 + e];
        float s = 0.f, ss = 0.f;
        #pragma unroll
        for (int e = 0; e < 8; ++e) { s += v[e]; ss += v[e] * v[e]; }
        s += __shfl_xor(s, 1); ss += __shfl_xor(ss, 1);
        s += __shfl_xor(s, 2); ss += __shfl_xor(ss, 2);
        const float mu  = s * (1.f / 32.f);
        const float var = ss * (1.f / 32.f) - mu * mu;
        const float rs  = rsqrtf(var + 1e-5f);
        union { ushort us[8]; uint4 q; } pk;
        #pragma unroll
        for (int e = 0; e < 8; ++e) {
            const int c = seg * 8 + e;
            pk.us[e] = f2bf((v[e] - mu) * rs * onw[c] + onb[c]);
        }
        *(uint4*)&An[r][seg * 8] = pk.q;
    }
    __syncthreads();   // An/Bw ready; Ol dead beyond this point

    // ---- MFMA: wave w -> rows w*16..+15, 128 outputs, single k-step ----
    const int lane = tid & 63, wave = tid >> 6;
    const int fr = lane & 15, hi = lane >> 4;
    const int wrow = wave * 16;

    const bf16x8 af = *(const bf16x8*)&An[wrow + fr][hi * 8];
    f32x4 acc[8];
    #pragma unroll
    for (int n = 0; n < 8; ++n) {
        const bf16x8 bv = *(const bf16x8*)&Bw[n * 16 + fr][hi * 8];
        acc[n] = __builtin_amdgcn_mfma_f32_16x16x32_bf16(
            af, bv, (f32x4){0.f, 0.f, 0.f, 0.f}, 0, 0, 0);
    }

    // ---- +bias -> Res (aliases dead Ol) ----
    #pragma unroll
    for (int n = 0; n < 8; ++n) {
        const int ch = n * 16 + fr;
        const float obv = obias[ch];
        #pragma unroll
        for (int q = 0; q < 4; ++q)
            u.Res[wrow + hi * 4 + q][ch] = acc[n][q] + obv;
    }
    __syncthreads();

    // ---- Res * gate -> out, coalesced ----
    #pragma unroll
    for (int it = 0; it < 8; ++it) {
        const int idx = it * 256 + tid;          // 2048 float4 chunks
        const int r = idx >> 5, cq = (idx & 31) * 4;
        float4 v4 = *(const float4*)&u.Res[r][cq];
        union { uint2 d; ushort us[4]; } g;
        g.d = *(const uint2*)&gate[(rowbase + r) * ZD + cq];
        v4.x *= bf2f(g.us[0]); v4.y *= bf2f(g.us[1]);
        v4.z *= bf2f(g.us[2]); v4.w *= bf2f(g.us[3]);
        *(float4*)&out[(rowbase + r) * ZD + cq] = v4;
    }
}

extern "C" void kernel_launch(void* const* d_in, const int* in_sizes, int n_in,
                              void* d_out, int out_size, void* d_ws, size_t ws_size,
                              hipStream_t stream) {
    (void)in_sizes; (void)n_in; (void)out_size; (void)ws_size;
    const float* z   = (const float*)d_in[0];
    const float* nw  = (const float*)d_in[1];
    const float* nb  = (const float*)d_in[2];
    const float* onw = (const float*)d_in[3];
    const float* onb = (const float*)d_in[4];
    const float* aw  = (const float*)d_in[5];
    const float* ab  = (const float*)d_in[6];
    const float* agw = (const float*)d_in[7];
    const float* agb = (const float*)d_in[8];
    const float* gw  = (const float*)d_in[9];
    const float* gb  = (const float*)d_in[10];
    const float* ow  = (const float*)d_in[11];
    const float* ob  = (const float*)d_in[12];

    char* ws = (char*)d_ws;
    ushort* a_t  = (ushort*)ws;                                   // 37,748,736 B
    ushort* gate = (ushort*)(ws + 37748736);                      // 150,994,944 B
    float*  obuf = (float*)(ws + 37748736 + 150994944);           // 75,497,472 B
    ushort* wcat = (ushort*)obuf;  // aliased: live only k0->k1, k2 clobbers

    k0_wconv<<<96, 256, 0, stream>>>(aw, agw, gw, wcat);
    k1_ln_proj<<<LL / 64, 256, 0, stream>>>(z, nw, nb, wcat, ab, agb, gb,
                                            a_t, gate);
    k2_einsum<<<dim3(12, 12, 32), 256, 0, stream>>>(a_t, obuf);
    k3_out<<<LL / 64, 256, 0, stream>>>(obuf, onw, onb, ow, ob, gate,
                                        (float*)d_out);
}